// Round 2
// baseline (483.180 us; speedup 1.0000x reference)
//
#include <hip/hip_runtime.h>

typedef unsigned short u16;
typedef unsigned int u32;
typedef __attribute__((ext_vector_type(8))) short bf16x8;   // 8 bf16 = 4 VGPRs (MFMA A/B frag)
typedef __attribute__((ext_vector_type(4))) float f32x4;    // MFMA C/D frag

__device__ __forceinline__ u16 f2bf(float f) {
    u32 u = __float_as_uint(f);
    return (u16)((u + 0x7FFFu + ((u >> 16) & 1u)) >> 16);   // round-to-nearest-even
}

// fast GELU via sigmoid identity: 0.5x(1+tanh(y)) = x*u/(u+1), u=e^{2y}.
// ~10 VALU insts (v_rcp instead of IEEE divide; |err| vs exact erf-gelu ~3e-3)
__device__ __forceinline__ float fast_gelu(float x) {
    const float t = x * x;
    // 2*0.79788456*(x + 0.044715 x^3) = x*(1.59576912 + 0.07135482 x^2)
    const float y2 = x * __builtin_fmaf(0.0713548214f, t, 1.5957691216057308f);
    const float u = __expf(fminf(y2, 80.f));                 // overflow-capped
    return x * u * __builtin_amdgcn_rcpf(u + 1.f);
}

// ---------------------------------------------------------------------------
// Prep: cast fp32 -> bf16 streaming (feats / dw_w)
// ---------------------------------------------------------------------------
__global__ __launch_bounds__(256) void cast_feats_k(
    const float* __restrict__ src, u16* __restrict__ dst, int n4)
{
    const int e = blockIdx.x * 256 + threadIdx.x;
    if (e >= n4) return;
    const float4 v = *(const float4*)(src + (size_t)e * 4);
    uint2 o;
    o.x = (u32)f2bf(v.x) | ((u32)f2bf(v.y) << 16);
    o.y = (u32)f2bf(v.z) | ((u32)f2bf(v.w) << 16);
    *(uint2*)(dst + (size_t)e * 4) = o;
}

// ---------------------------------------------------------------------------
// Kernel A: sparse depthwise conv + bias + LayerNorm.  TWO sites per wave:
// packed dual prefix-sum compaction, interleaved gather streams.
// ---------------------------------------------------------------------------
__global__ __launch_bounds__(256) void dwln_k(
    const u16* __restrict__ featsb, const int* __restrict__ nb,
    const u16* __restrict__ dwwb, const float* __restrict__ dw_b,
    const float* __restrict__ ln_g, const float* __restrict__ ln_b,
    u16* __restrict__ xln, int nsites)
{
    __shared__ int lists[8][348];
    const int w = threadIdx.x >> 6;
    const int lane = threadIdx.x & 63;
    const int s0 = blockIdx.x * 8 + w * 2;
    if (s0 >= nsites) return;
    const bool two = (s0 + 1) < nsites;
    const int* rowA = nb + (size_t)s0 * 343;
    const int* rowB = nb + (size_t)(two ? s0 + 1 : s0) * 343;
    int idxA[6], idxB[6];
    #pragma unroll
    for (int j = 0; j < 5; ++j) {
        idxA[j] = rowA[lane + j * 64];
        const int vb = rowB[lane + j * 64];
        idxB[j] = two ? vb : nsites;
    }
    idxA[5] = (lane < 23) ? rowA[320 + lane] : nsites;
    idxB[5] = (two && lane < 23) ? rowB[320 + lane] : nsites;
    int cA = 0, cB = 0;
    #pragma unroll
    for (int i = 0; i < 6; ++i) {
        cA += (idxA[i] < nsites) ? 1 : 0;
        cB += (idxB[i] < nsites) ? 1 : 0;
    }
    const int packed = cA | (cB << 16);
    int pre = packed;
    #pragma unroll
    for (int off = 1; off < 64; off <<= 1) {
        const int v = __shfl_up(pre, off, 64);
        if (lane >= off) pre += v;
    }
    const int tot = __shfl(pre, 63, 64);
    const int cntA = tot & 0xFFFF, cntB = tot >> 16;
    pre -= packed;
    int pA = pre & 0xFFFF, pB = pre >> 16;
    #pragma unroll
    for (int i = 0; i < 6; ++i) {
        const int k = (i < 5) ? (lane + i * 64) : (320 + lane);
        if (idxA[i] < nsites) lists[w * 2][pA++] = idxA[i] | (k << 17);
        if (idxB[i] < nsites) lists[w * 2 + 1][pB++] = idxB[i] | (k << 17);
    }
    float xA0 = 0.f, xA1 = 0.f, xB0 = 0.f, xB1 = 0.f;
    const int mx = (cntA > cntB) ? cntA : cntB;
    for (int base = 0; base < mx; base += 4) {
        u32 fa[4], wa[4], fb[4], wb[4];
        #pragma unroll
        for (int i = 0; i < 4; ++i) {
            if (base + i < cntA) {
                const int p = lists[w * 2][base + i];
                fa[i] = *(const u32*)(featsb + (size_t)(p & 0x1FFFF) * 128 + lane * 2);
                wa[i] = *(const u32*)(dwwb + (size_t)(p >> 17) * 128 + lane * 2);
            } else { fa[i] = 0u; wa[i] = 0u; }
            if (base + i < cntB) {
                const int p = lists[w * 2 + 1][base + i];
                fb[i] = *(const u32*)(featsb + (size_t)(p & 0x1FFFF) * 128 + lane * 2);
                wb[i] = *(const u32*)(dwwb + (size_t)(p >> 17) * 128 + lane * 2);
            } else { fb[i] = 0u; wb[i] = 0u; }
        }
        #pragma unroll
        for (int i = 0; i < 4; ++i) {
            xA0 += __uint_as_float(fa[i] << 16) * __uint_as_float(wa[i] << 16);
            xA1 += __uint_as_float(fa[i] & 0xFFFF0000u) * __uint_as_float(wa[i] & 0xFFFF0000u);
            xB0 += __uint_as_float(fb[i] << 16) * __uint_as_float(wb[i] << 16);
            xB1 += __uint_as_float(fb[i] & 0xFFFF0000u) * __uint_as_float(wb[i] & 0xFFFF0000u);
        }
    }
    const float2 bv = *(const float2*)(dw_b + lane * 2);
    const float2 gv = *(const float2*)(ln_g + lane * 2);
    const float2 lbv = *(const float2*)(ln_b + lane * 2);
    #pragma unroll
    for (int sidx = 0; sidx < 2; ++sidx) {
        if (sidx == 1 && !two) break;
        float a0 = (sidx == 0) ? xA0 : xB0;
        float a1 = (sidx == 0) ? xA1 : xB1;
        a0 += bv.x; a1 += bv.y;
        float s = a0 + a1, ss = a0 * a0 + a1 * a1;
        #pragma unroll
        for (int off = 32; off > 0; off >>= 1) {
            s += __shfl_xor(s, off, 64);
            ss += __shfl_xor(ss, off, 64);
        }
        const float mean = s * (1.f / 128.f);
        const float var = ss * (1.f / 128.f) - mean * mean;
        const float rstd = rsqrtf(fmaxf(var, 0.f) + 1e-6f);
        const float y0 = (a0 - mean) * rstd * gv.x + lbv.x;
        const float y1 = (a1 - mean) * rstd * gv.y + lbv.y;
        *(u32*)(xln + (size_t)(s0 + sidx) * 128 + lane * 2) =
            (u32)f2bf(y0) | ((u32)f2bf(y1) << 16);
    }
}

// ---------------------------------------------------------------------------
// w1 fp32 [128,512] -> w1t bf16 [512,128] (channel-major for MFMA frag reads)
// ---------------------------------------------------------------------------
__global__ __launch_bounds__(256) void transpose_w1_k(
    const float* __restrict__ w1, u16* __restrict__ w1t)
{
    const int e = blockIdx.x * 256 + threadIdx.x;    // 65536 total
    const int n = e >> 7, k = e & 127;
    w1t[e] = f2bf(w1[k * 512 + n]);
}

// ---------------------------------------------------------------------------
// Kernel B: h = gelu(xln @ w1 + b1) [N,512] bf16 + per-channel sum(h^2).
// OPERAND-SWAPPED MFMA (A=w1t channel rows, B=xln site rows).
// B (streaming xln) keeps an explicit 2-deep register double-buffer; A is
// L2-hot (128 KB) and loads un-prefetched to fit the 5-waves/EU VGPR cap.
// ---------------------------------------------------------------------------
__global__ __launch_bounds__(256, 5) void gemm1_k(
    const u16* __restrict__ xln, const u16* __restrict__ w1t,
    const float* __restrict__ b1, u16* __restrict__ h,
    float* __restrict__ gx_sq, int nsites)
{
    __shared__ float s_red[128];
    const int t = threadIdx.x;
    const int n0 = blockIdx.x * 128;     // channel block
    const int m0 = blockIdx.y * 64;      // site block
    const int lane = t & 63;
    const int w = t >> 6;
    const int wn = w * 32;               // wave's 32-channel slice
    const int l15 = lane & 15, quad = lane >> 4;
    if (t < 128) s_red[t] = 0.f;
    __syncthreads();
    f32x4 acc[2][4];                     // [nt (chan 16-grp)][mt (site 16-grp)]
    #pragma unroll
    for (int i = 0; i < 2; ++i)
        #pragma unroll
        for (int j = 0; j < 4; ++j) acc[i][j] = f32x4{0.f, 0.f, 0.f, 0.f};
    const u16* a_base = w1t + (size_t)(n0 + wn + l15) * 128 + quad * 8;  // channel rows (L2-hot)
    const u16* b_base = xln + (size_t)(m0 + l15) * 128 + quad * 8;       // site rows (streaming)
    bf16x8 aC[2], bC[4], bN[4];
    #pragma unroll
    for (int mt = 0; mt < 4; ++mt) bC[mt] = *(const bf16x8*)(b_base + (size_t)mt * 16 * 128);
    #pragma unroll
    for (int ks = 0; ks < 4; ++ks) {
        const int koff = ks * 32;
        #pragma unroll
        for (int nt = 0; nt < 2; ++nt)
            aC[nt] = *(const bf16x8*)(a_base + (size_t)nt * 16 * 128 + koff);
        if (ks < 3) {
            #pragma unroll
            for (int mt = 0; mt < 4; ++mt)
                bN[mt] = *(const bf16x8*)(b_base + (size_t)mt * 16 * 128 + koff + 32);
        }
        #pragma unroll
        for (int nt = 0; nt < 2; ++nt)
            #pragma unroll
            for (int mt = 0; mt < 4; ++mt)
                acc[nt][mt] = __builtin_amdgcn_mfma_f32_16x16x32_bf16(aC[nt], bC[mt], acc[nt][mt], 0, 0, 0);
        if (ks < 3) {
            #pragma unroll
            for (int mt = 0; mt < 4; ++mt) bC[mt] = bN[mt];
        }
    }
    // epilogue: lane holds channels chb..chb+3 (consecutive) for site m0+mt*16+l15
    float ssl[2][4] = {{0.f,0.f,0.f,0.f},{0.f,0.f,0.f,0.f}};
    #pragma unroll
    for (int nt = 0; nt < 2; ++nt) {
        const int chb = n0 + wn + nt * 16 + quad * 4;        // global channel base
        const float4 b1v = *(const float4*)(b1 + chb);
        #pragma unroll
        for (int mt = 0; mt < 4; ++mt) {
            const int site = m0 + mt * 16 + l15;
            if (site < nsites) {
                float v[4];
                #pragma unroll
                for (int rg = 0; rg < 4; ++rg) {
                    v[rg] = fast_gelu(acc[nt][mt][rg] + ((const float*)&b1v)[rg]);
                    ssl[nt][rg] += v[rg] * v[rg];
                }
                uint2 o;
                o.x = (u32)f2bf(v[0]) | ((u32)f2bf(v[1]) << 16);
                o.y = (u32)f2bf(v[2]) | ((u32)f2bf(v[3]) << 16);
                *(uint2*)(h + (size_t)site * 512 + chb) = o;
            }
        }
    }
    // reduce ssl over the 16 l15-lanes (same channel), then 4 lanes/wave do LDS atomics
    #pragma unroll
    for (int nt = 0; nt < 2; ++nt)
        #pragma unroll
        for (int rg = 0; rg < 4; ++rg) {
            float v = ssl[nt][rg];
            v += __shfl_xor(v, 1, 64);
            v += __shfl_xor(v, 2, 64);
            v += __shfl_xor(v, 4, 64);
            v += __shfl_xor(v, 8, 64);
            if (l15 == 0) atomicAdd(&s_red[wn + nt * 16 + quad * 4 + rg], v);
        }
    __syncthreads();
    if (t < 128) atomicAdd(&gx_sq[n0 + t], s_red[t]);
}

// ---------------------------------------------------------------------------
// Kernel C0: b_eff_acc = grn_b @ w2  (independent of GRN stats -> off the
// serial gemm1->scale->gemm2 chain; 8 blocks, coalesced, atomic combine)
// ---------------------------------------------------------------------------
__global__ __launch_bounds__(256) void beff_k(
    const float* __restrict__ grn_b, const float* __restrict__ w2,
    float* __restrict__ b_eff)
{
    __shared__ float red[256];
    const int t = threadIdx.x;
    const int dc = t & 127, part = t >> 7;
    const int c0 = blockIdx.x * 64 + part * 32;
    float p = 0.f;
    #pragma unroll 8
    for (int i = 0; i < 32; ++i) {
        const int c = c0 + i;
        p += grn_b[c] * w2[(size_t)c * 128 + dc];
    }
    red[t] = p;
    __syncthreads();
    if (t < 128) atomicAdd(&b_eff[t], red[t] + red[t + 128]);
}

// ---------------------------------------------------------------------------
// Kernel C1: GRN scale only (one tiny block).
// ---------------------------------------------------------------------------
__global__ __launch_bounds__(512) void grn_scale_k(
    const float* __restrict__ gx_sq, const float* __restrict__ grn_g,
    float* __restrict__ scale)
{
    __shared__ float red[512];
    const int t = threadIdx.x;
    const float g = sqrtf(gx_sq[t]);
    red[t] = g;
    __syncthreads();
    #pragma unroll
    for (int off = 256; off > 0; off >>= 1) {
        if (t < off) red[t] += red[t + off];
        __syncthreads();
    }
    const float mean = red[0] * (1.f / 512.f);
    scale[t] = grn_g[t] * (g / (mean + 1e-6f)) + 1.f;
}

// ---------------------------------------------------------------------------
// Kernel C2: w2t[dc][c] = bf16(scale[c] * w2[c][dc])  (coalesced writes)
// ---------------------------------------------------------------------------
__global__ __launch_bounds__(256) void w2t_k(
    const float* __restrict__ scale, const float* __restrict__ w2,
    u16* __restrict__ w2t)
{
    const int e = blockIdx.x * 256 + threadIdx.x;    // 65536
    const int c = e & 511, dc = e >> 9;
    w2t[e] = f2bf(scale[c] * w2[(size_t)c * 128 + dc]);
}

// ---------------------------------------------------------------------------
// Kernel D: out = feats + h_scaled @ w2 + b_eff + b2 (fp32 out).
// OPERAND-SWAPPED (A=w2t output-channel rows, B=h site rows) -> float4
// feats/out epilogue.  B (streaming h) keeps explicit 2-deep double-buffer;
// A is L2-hot and un-prefetched to fit the 5-waves/EU VGPR cap.
// ---------------------------------------------------------------------------
__global__ __launch_bounds__(256, 5) void gemm2_k(
    const u16* __restrict__ h, const u16* __restrict__ w2t,
    const float* __restrict__ b_eff, const float* __restrict__ b2,
    const float* __restrict__ feats,
    float* __restrict__ out, int nsites)
{
    const int t = threadIdx.x;
    const int m0 = blockIdx.x * 64;
    const int lane = t & 63;
    const int w = t >> 6;
    const int wn = w * 32;               // wave's 32 output channels
    const int l15 = lane & 15, quad = lane >> 4;
    f32x4 acc[2][4];                     // [nt (out-chan 16-grp)][mt (site 16-grp)]
    #pragma unroll
    for (int i = 0; i < 2; ++i)
        #pragma unroll
        for (int j = 0; j < 4; ++j) acc[i][j] = f32x4{0.f, 0.f, 0.f, 0.f};
    const u16* a_base = w2t + (size_t)(wn + l15) * 512 + quad * 8;   // out-channel rows (L2-hot)
    const u16* b_base = h + (size_t)(m0 + l15) * 512 + quad * 8;     // site rows (streaming)
    bf16x8 aC[2], bC[4], bN[4];
    #pragma unroll
    for (int mt = 0; mt < 4; ++mt) bC[mt] = *(const bf16x8*)(b_base + (size_t)mt * 16 * 512);
    #pragma unroll
    for (int ks = 0; ks < 16; ++ks) {
        const int koff = ks * 32;
        #pragma unroll
        for (int nt = 0; nt < 2; ++nt)
            aC[nt] = *(const bf16x8*)(a_base + (size_t)nt * 16 * 512 + koff);
        if (ks < 15) {
            #pragma unroll
            for (int mt = 0; mt < 4; ++mt)
                bN[mt] = *(const bf16x8*)(b_base + (size_t)mt * 16 * 512 + koff + 32);
        }
        #pragma unroll
        for (int nt = 0; nt < 2; ++nt)
            #pragma unroll
            for (int mt = 0; mt < 4; ++mt)
                acc[nt][mt] = __builtin_amdgcn_mfma_f32_16x16x32_bf16(aC[nt], bC[mt], acc[nt][mt], 0, 0, 0);
        if (ks < 15) {
            #pragma unroll
            for (int mt = 0; mt < 4; ++mt) bC[mt] = bN[mt];
        }
    }
    // epilogue: lane holds out-channels chb..chb+3 for site m0+mt*16+l15
    #pragma unroll
    for (int nt = 0; nt < 2; ++nt) {
        const int chb = wn + nt * 16 + quad * 4;
        const float4 bev = *(const float4*)(b_eff + chb);
        const float4 b2v = *(const float4*)(b2 + chb);
        #pragma unroll
        for (int mt = 0; mt < 4; ++mt) {
            const int site = m0 + mt * 16 + l15;
            if (site < nsites) {
                const float4 fv = *(const float4*)(feats + (size_t)site * 128 + chb);
                float4 o;
                o.x = acc[nt][mt][0] + bev.x + b2v.x + fv.x;
                o.y = acc[nt][mt][1] + bev.y + b2v.y + fv.y;
                o.z = acc[nt][mt][2] + bev.z + b2v.z + fv.z;
                o.w = acc[nt][mt][3] + bev.w + b2v.w + fv.w;
                *(float4*)(out + (size_t)site * 128 + chb) = o;
            }
        }
    }
}

// ---------------------------------------------------------------------------
extern "C" void kernel_launch(void* const* d_in, const int* in_sizes, int n_in,
                              void* d_out, int out_size, void* d_ws, size_t ws_size,
                              hipStream_t stream) {
    const float* feats = (const float*)d_in[0];    // [N,128] f32
    const int* nb      = (const int*)d_in[1];      // [N,343] int32
    const float* dw_w  = (const float*)d_in[2];    // [343,128] f32
    const float* dw_b  = (const float*)d_in[3];    // [128]
    const float* ln_g  = (const float*)d_in[4];    // [128]
    const float* ln_b  = (const float*)d_in[5];    // [128]
    const float* w1    = (const float*)d_in[6];    // [128,512]
    const float* b1    = (const float*)d_in[7];    // [512]
    const float* grn_g = (const float*)d_in[8];    // [512]
    const float* grn_b = (const float*)d_in[9];    // [512]
    const float* w2    = (const float*)d_in[10];   // [512,128]
    const float* b2    = (const float*)d_in[11];   // [128]
    float* out = (float*)d_out;
    const int nsites = in_sizes[0] / 128;

    char* ws = (char*)d_ws;
    size_t off = 0;
    u16* xln   = (u16*)(ws + off);  off += (((size_t)(nsites + 128) * 128 * 2) + 255) & ~(size_t)255;
    u16* h     = (u16*)(ws + off);  off += (((size_t)(nsites + 128) * 512 * 2) + 255) & ~(size_t)255;
    u16* featsb= (u16*)(ws + off);  off += (((size_t)nsites * 128 * 2) + 255) & ~(size_t)255;
    u16* dwwb  = (u16*)(ws + off);  off += 343 * 128 * 2 + 128;
    u16* w1t   = (u16*)(ws + off);  off += 512 * 128 * 2;
    u16* w2t   = (u16*)(ws + off);  off += 128 * 512 * 2;
    float* gx_sq = (float*)(ws + off); off += 512 * 4;
    float* scale = (float*)(ws + off); off += 512 * 4;
    float* b_eff = (float*)(ws + off); off += 128 * 4;

    hipMemsetAsync(gx_sq, 0, 512 * sizeof(float), stream);
    hipMemsetAsync(b_eff, 0, 128 * sizeof(float), stream);
    const int nfeat4 = nsites * 32;
    cast_feats_k<<<(nfeat4 + 255) / 256, 256, 0, stream>>>(feats, featsb, nfeat4);
    const int ndww4 = 343 * 32;
    cast_feats_k<<<(ndww4 + 255) / 256, 256, 0, stream>>>(dw_w, dwwb, ndww4);
    transpose_w1_k<<<256, 256, 0, stream>>>(w1, w1t);
    beff_k<<<8, 256, 0, stream>>>(grn_b, w2, b_eff);
    dwln_k<<<(nsites + 7) / 8, 256, 0, stream>>>(featsb, nb, dwwb, dw_b, ln_g, ln_b, xln, nsites);
    const int m1blocks = (nsites + 63) / 64;
    gemm1_k<<<dim3(4, m1blocks), 256, 0, stream>>>(xln, w1t, b1, h, gx_sq, nsites);
    grn_scale_k<<<1, 512, 0, stream>>>(gx_sq, grn_g, scale);
    w2t_k<<<256, 256, 0, stream>>>(scale, w2, w2t);
    const int m2blocks = (nsites + 63) / 64;
    gemm2_k<<<m2blocks, 256, 0, stream>>>(h, w2t, b_eff, b2, feats, out, nsites);
}

// Round 3
// 410.971 us; speedup vs baseline: 1.1757x; 1.1757x over previous
//
#include <hip/hip_runtime.h>

typedef unsigned short u16;
typedef unsigned int u32;
typedef __attribute__((ext_vector_type(8))) short bf16x8;   // 8 bf16 = 4 VGPRs (MFMA A/B frag)
typedef __attribute__((ext_vector_type(4))) float f32x4;    // MFMA C/D frag

__device__ __forceinline__ u16 f2bf(float f) {
    u32 u = __float_as_uint(f);
    return (u16)((u + 0x7FFFu + ((u >> 16) & 1u)) >> 16);   // round-to-nearest-even
}

// fast GELU via sigmoid identity: 0.5x(1+tanh(y)) = x*u/(u+1), u=e^{2y}.
__device__ __forceinline__ float fast_gelu(float x) {
    const float t = x * x;
    const float y2 = x * __builtin_fmaf(0.0713548214f, t, 1.5957691216057308f);
    const float u = __expf(fminf(y2, 80.f));                 // overflow-capped
    return x * u * __builtin_amdgcn_rcpf(u + 1.f);
}

// async global->LDS, 16B per lane (dest = uniform base + lane*16, src per-lane)
__device__ __forceinline__ void gload_lds16(const u16* g, u16* l) {
    __builtin_amdgcn_global_load_lds(
        (const __attribute__((address_space(1))) void*)g,
        (__attribute__((address_space(3))) void*)l, 16, 0, 0);
}

// ---------------------------------------------------------------------------
// Prep: cast fp32 -> bf16 streaming (feats / dw_w)
// ---------------------------------------------------------------------------
__global__ __launch_bounds__(256) void cast_feats_k(
    const float* __restrict__ src, u16* __restrict__ dst, int n4)
{
    const int e = blockIdx.x * 256 + threadIdx.x;
    if (e >= n4) return;
    const float4 v = *(const float4*)(src + (size_t)e * 4);
    uint2 o;
    o.x = (u32)f2bf(v.x) | ((u32)f2bf(v.y) << 16);
    o.y = (u32)f2bf(v.z) | ((u32)f2bf(v.w) << 16);
    *(uint2*)(dst + (size_t)e * 4) = o;
}

// ---------------------------------------------------------------------------
// Kernel A: sparse depthwise conv + bias + LayerNorm.  TWO sites per wave:
// packed dual prefix-sum compaction, interleaved gather streams.
// ---------------------------------------------------------------------------
__global__ __launch_bounds__(256) void dwln_k(
    const u16* __restrict__ featsb, const int* __restrict__ nb,
    const u16* __restrict__ dwwb, const float* __restrict__ dw_b,
    const float* __restrict__ ln_g, const float* __restrict__ ln_b,
    u16* __restrict__ xln, int nsites)
{
    __shared__ int lists[8][348];
    const int w = threadIdx.x >> 6;
    const int lane = threadIdx.x & 63;
    const int s0 = blockIdx.x * 8 + w * 2;
    if (s0 >= nsites) return;
    const bool two = (s0 + 1) < nsites;
    const int* rowA = nb + (size_t)s0 * 343;
    const int* rowB = nb + (size_t)(two ? s0 + 1 : s0) * 343;
    int idxA[6], idxB[6];
    #pragma unroll
    for (int j = 0; j < 5; ++j) {
        idxA[j] = rowA[lane + j * 64];
        const int vb = rowB[lane + j * 64];
        idxB[j] = two ? vb : nsites;
    }
    idxA[5] = (lane < 23) ? rowA[320 + lane] : nsites;
    idxB[5] = (two && lane < 23) ? rowB[320 + lane] : nsites;
    int cA = 0, cB = 0;
    #pragma unroll
    for (int i = 0; i < 6; ++i) {
        cA += (idxA[i] < nsites) ? 1 : 0;
        cB += (idxB[i] < nsites) ? 1 : 0;
    }
    const int packed = cA | (cB << 16);
    int pre = packed;
    #pragma unroll
    for (int off = 1; off < 64; off <<= 1) {
        const int v = __shfl_up(pre, off, 64);
        if (lane >= off) pre += v;
    }
    const int tot = __shfl(pre, 63, 64);
    const int cntA = tot & 0xFFFF, cntB = tot >> 16;
    pre -= packed;
    int pA = pre & 0xFFFF, pB = pre >> 16;
    #pragma unroll
    for (int i = 0; i < 6; ++i) {
        const int k = (i < 5) ? (lane + i * 64) : (320 + lane);
        if (idxA[i] < nsites) lists[w * 2][pA++] = idxA[i] | (k << 17);
        if (idxB[i] < nsites) lists[w * 2 + 1][pB++] = idxB[i] | (k << 17);
    }
    float xA0 = 0.f, xA1 = 0.f, xB0 = 0.f, xB1 = 0.f;
    const int mx = (cntA > cntB) ? cntA : cntB;
    for (int base = 0; base < mx; base += 4) {
        u32 fa[4], wa[4], fb[4], wb[4];
        #pragma unroll
        for (int i = 0; i < 4; ++i) {
            if (base + i < cntA) {
                const int p = lists[w * 2][base + i];
                fa[i] = *(const u32*)(featsb + (size_t)(p & 0x1FFFF) * 128 + lane * 2);
                wa[i] = *(const u32*)(dwwb + (size_t)(p >> 17) * 128 + lane * 2);
            } else { fa[i] = 0u; wa[i] = 0u; }
            if (base + i < cntB) {
                const int p = lists[w * 2 + 1][base + i];
                fb[i] = *(const u32*)(featsb + (size_t)(p & 0x1FFFF) * 128 + lane * 2);
                wb[i] = *(const u32*)(dwwb + (size_t)(p >> 17) * 128 + lane * 2);
            } else { fb[i] = 0u; wb[i] = 0u; }
        }
        #pragma unroll
        for (int i = 0; i < 4; ++i) {
            xA0 += __uint_as_float(fa[i] << 16) * __uint_as_float(wa[i] << 16);
            xA1 += __uint_as_float(fa[i] & 0xFFFF0000u) * __uint_as_float(wa[i] & 0xFFFF0000u);
            xB0 += __uint_as_float(fb[i] << 16) * __uint_as_float(wb[i] << 16);
            xB1 += __uint_as_float(fb[i] & 0xFFFF0000u) * __uint_as_float(wb[i] & 0xFFFF0000u);
        }
    }
    const float2 bv = *(const float2*)(dw_b + lane * 2);
    const float2 gv = *(const float2*)(ln_g + lane * 2);
    const float2 lbv = *(const float2*)(ln_b + lane * 2);
    #pragma unroll
    for (int sidx = 0; sidx < 2; ++sidx) {
        if (sidx == 1 && !two) break;
        float a0 = (sidx == 0) ? xA0 : xB0;
        float a1 = (sidx == 0) ? xA1 : xB1;
        a0 += bv.x; a1 += bv.y;
        float s = a0 + a1, ss = a0 * a0 + a1 * a1;
        #pragma unroll
        for (int off = 32; off > 0; off >>= 1) {
            s += __shfl_xor(s, off, 64);
            ss += __shfl_xor(ss, off, 64);
        }
        const float mean = s * (1.f / 128.f);
        const float var = ss * (1.f / 128.f) - mean * mean;
        const float rstd = rsqrtf(fmaxf(var, 0.f) + 1e-6f);
        const float y0 = (a0 - mean) * rstd * gv.x + lbv.x;
        const float y1 = (a1 - mean) * rstd * gv.y + lbv.y;
        *(u32*)(xln + (size_t)(s0 + sidx) * 128 + lane * 2) =
            (u32)f2bf(y0) | ((u32)f2bf(y1) << 16);
    }
}

// ---------------------------------------------------------------------------
// w1 fp32 [128,512] -> w1t bf16 [512,128] (channel-major for MFMA frag reads)
// ---------------------------------------------------------------------------
__global__ __launch_bounds__(256) void transpose_w1_k(
    const float* __restrict__ w1, u16* __restrict__ w1t)
{
    const int e = blockIdx.x * 256 + threadIdx.x;    // 65536 total
    const int n = e >> 7, k = e & 127;
    w1t[e] = f2bf(w1[k * 512 + n]);
}

// ---------------------------------------------------------------------------
// Kernel B: h = gelu(xln @ w1 + b1) [N,512] bf16 + per-channel sum(h^2).
// OPERAND-SWAPPED MFMA (A=w1t channel rows from L2, B=xln site rows).
// xln tile [64][128] staged to LDS ONCE via global_load_lds (async, 16B),
// XOR-swizzled via pre-swizzled GLOBAL source (rule: linear dest +
// inverse-swz source + swz on read).  16 KB in flight per block at launch.
// ---------------------------------------------------------------------------
__global__ __launch_bounds__(256, 4) void gemm1_k(
    const u16* __restrict__ xln, const u16* __restrict__ w1t,
    const float* __restrict__ b1, u16* __restrict__ h,
    float* __restrict__ gx_sq, int nsites)
{
    __shared__ u16 xb[64 * 128];         // [site r][stored chunk s], s = c ^ (r&15)
    __shared__ float s_red[128];
    const int t = threadIdx.x;
    const int n0 = blockIdx.x * 128;     // channel block
    const int m0 = blockIdx.y * 64;      // site block
    const int lane = t & 63;
    const int w = t >> 6;
    const int wn = w * 32;               // wave's 32-channel slice
    const int l15 = lane & 15, quad = lane >> 4;
    if (t < 128) s_red[t] = 0.f;
    // --- stage xln tile: 4 instrs/wave, each covers 4 rows (1 KB) ---
    #pragma unroll
    for (int i = 0; i < 4; ++i) {
        const int r = w * 16 + i * 4 + (lane >> 4);          // tile row this lane loads
        const int c = (lane & 15) ^ (r & 15);                // logical chunk for stored slot
        gload_lds16(xln + (size_t)(m0 + r) * 128 + c * 8,
                    &xb[(w * 16 + i * 4) * 128]);
    }
    f32x4 acc[2][4];                     // [nt (chan 16-grp)][mt (site 16-grp)]
    #pragma unroll
    for (int i = 0; i < 2; ++i)
        #pragma unroll
        for (int j = 0; j < 4; ++j) acc[i][j] = f32x4{0.f, 0.f, 0.f, 0.f};
    const u16* a_base = w1t + (size_t)(n0 + wn + l15) * 128 + quad * 8;  // channel rows (L2-hot)
    bf16x8 aC[2];
    #pragma unroll
    for (int nt = 0; nt < 2; ++nt) aC[nt] = *(const bf16x8*)(a_base + (size_t)nt * 16 * 128);
    asm volatile("s_waitcnt vmcnt(0)" ::: "memory");
    __syncthreads();                     // tile landed for all waves
    #pragma unroll
    for (int ks = 0; ks < 4; ++ks) {
        bf16x8 aN[2];
        if (ks < 3) {
            #pragma unroll
            for (int nt = 0; nt < 2; ++nt)
                aN[nt] = *(const bf16x8*)(a_base + (size_t)nt * 16 * 128 + (ks + 1) * 32);
        }
        bf16x8 b[4];
        #pragma unroll
        for (int mt = 0; mt < 4; ++mt) {
            const int r = mt * 16 + l15;
            b[mt] = *(const bf16x8*)(&xb[r * 128 + (((ks * 4 + quad) ^ l15) << 3)]);
        }
        #pragma unroll
        for (int nt = 0; nt < 2; ++nt)
            #pragma unroll
            for (int mt = 0; mt < 4; ++mt)
                acc[nt][mt] = __builtin_amdgcn_mfma_f32_16x16x32_bf16(aC[nt], b[mt], acc[nt][mt], 0, 0, 0);
        if (ks < 3) {
            #pragma unroll
            for (int nt = 0; nt < 2; ++nt) aC[nt] = aN[nt];
        }
    }
    // epilogue: lane holds channels chb..chb+3 (consecutive) for site m0+mt*16+l15
    float ssl[2][4] = {{0.f,0.f,0.f,0.f},{0.f,0.f,0.f,0.f}};
    #pragma unroll
    for (int nt = 0; nt < 2; ++nt) {
        const int chb = n0 + wn + nt * 16 + quad * 4;        // global channel base
        const float4 b1v = *(const float4*)(b1 + chb);
        #pragma unroll
        for (int mt = 0; mt < 4; ++mt) {
            const int site = m0 + mt * 16 + l15;
            if (site < nsites) {
                float v[4];
                #pragma unroll
                for (int rg = 0; rg < 4; ++rg) {
                    v[rg] = fast_gelu(acc[nt][mt][rg] + ((const float*)&b1v)[rg]);
                    ssl[nt][rg] += v[rg] * v[rg];
                }
                uint2 o;
                o.x = (u32)f2bf(v[0]) | ((u32)f2bf(v[1]) << 16);
                o.y = (u32)f2bf(v[2]) | ((u32)f2bf(v[3]) << 16);
                *(uint2*)(h + (size_t)site * 512 + chb) = o;
            }
        }
    }
    // reduce ssl over the 16 l15-lanes (same channel), then 4 lanes/wave do LDS atomics
    #pragma unroll
    for (int nt = 0; nt < 2; ++nt)
        #pragma unroll
        for (int rg = 0; rg < 4; ++rg) {
            float v = ssl[nt][rg];
            v += __shfl_xor(v, 1, 64);
            v += __shfl_xor(v, 2, 64);
            v += __shfl_xor(v, 4, 64);
            v += __shfl_xor(v, 8, 64);
            if (l15 == 0) atomicAdd(&s_red[wn + nt * 16 + quad * 4 + rg], v);
        }
    __syncthreads();
    if (t < 128) atomicAdd(&gx_sq[n0 + t], s_red[t]);
}

// ---------------------------------------------------------------------------
// Kernel C0: b_eff_acc = grn_b @ w2
// ---------------------------------------------------------------------------
__global__ __launch_bounds__(256) void beff_k(
    const float* __restrict__ grn_b, const float* __restrict__ w2,
    float* __restrict__ b_eff)
{
    __shared__ float red[256];
    const int t = threadIdx.x;
    const int dc = t & 127, part = t >> 7;
    const int c0 = blockIdx.x * 64 + part * 32;
    float p = 0.f;
    #pragma unroll 8
    for (int i = 0; i < 32; ++i) {
        const int c = c0 + i;
        p += grn_b[c] * w2[(size_t)c * 128 + dc];
    }
    red[t] = p;
    __syncthreads();
    if (t < 128) atomicAdd(&b_eff[t], red[t] + red[t + 128]);
}

// ---------------------------------------------------------------------------
// Kernel C1: GRN scale only (one tiny block).
// ---------------------------------------------------------------------------
__global__ __launch_bounds__(512) void grn_scale_k(
    const float* __restrict__ gx_sq, const float* __restrict__ grn_g,
    float* __restrict__ scale)
{
    __shared__ float red[512];
    const int t = threadIdx.x;
    const float g = sqrtf(gx_sq[t]);
    red[t] = g;
    __syncthreads();
    #pragma unroll
    for (int off = 256; off > 0; off >>= 1) {
        if (t < off) red[t] += red[t + off];
        __syncthreads();
    }
    const float mean = red[0] * (1.f / 512.f);
    scale[t] = grn_g[t] * (g / (mean + 1e-6f)) + 1.f;
}

// ---------------------------------------------------------------------------
// Kernel C2: w2t[dc][c] = bf16(scale[c] * w2[c][dc])  (coalesced writes)
// ---------------------------------------------------------------------------
__global__ __launch_bounds__(256) void w2t_k(
    const float* __restrict__ scale, const float* __restrict__ w2,
    u16* __restrict__ w2t)
{
    const int e = blockIdx.x * 256 + threadIdx.x;    // 65536
    const int c = e & 511, dc = e >> 9;
    w2t[e] = f2bf(scale[c] * w2[(size_t)c * 128 + dc]);
}

// ---------------------------------------------------------------------------
// Kernel D: out = feats + h_scaled @ w2 + b_eff + b2 (fp32 out).
// OPERAND-SWAPPED (A=w2t out-channel rows from L2, B=h site rows).
// h streamed through LDS in 4 K-chunks of 128 (16 KB each, double-buffered):
// chunk t+1's 16 global_load_lds issued BEFORE computing chunk t ->
// 16 KB in flight per block, ~5 blocks/CU resident -> HBM-BW-limited.
// Same XOR swizzle (pre-swizzled source + swizzled ds_read).
// ---------------------------------------------------------------------------
__global__ __launch_bounds__(256, 4) void gemm2_k(
    const u16* __restrict__ h, const u16* __restrict__ w2t,
    const float* __restrict__ b_eff, const float* __restrict__ b2,
    const float* __restrict__ feats,
    float* __restrict__ out, int nsites)
{
    __shared__ u16 hb[2][64 * 128];      // double-buffered K-chunk tile
    const int t = threadIdx.x;
    const int m0 = blockIdx.x * 64;
    const int lane = t & 63;
    const int w = t >> 6;
    const int wn = w * 32;               // wave's 32 output channels
    const int l15 = lane & 15, quad = lane >> 4;
    const int r_st = w * 16 + (lane >> 4) * 4 ? 0 : 0;  // (unused guard)
    f32x4 acc[2][4];                     // [nt (out-chan 16-grp)][mt (site 16-grp)]
    #pragma unroll
    for (int i = 0; i < 2; ++i)
        #pragma unroll
        for (int j = 0; j < 4; ++j) acc[i][j] = f32x4{0.f, 0.f, 0.f, 0.f};
    const u16* a_base = w2t + (size_t)(wn + l15) * 512 + quad * 8;   // out-channel rows (L2-hot)

    // stage chunk tc (K cols [tc*128, tc*128+128)) into buffer b
    #define STAGE2(bsel, tc)                                                     \
        {                                                                        \
            _Pragma("unroll")                                                    \
            for (int i_ = 0; i_ < 4; ++i_) {                                     \
                const int r_ = w * 16 + i_ * 4 + (lane >> 4);                    \
                const int c_ = (lane & 15) ^ (r_ & 15);                          \
                gload_lds16(h + (size_t)(m0 + r_) * 512 + (tc) * 128 + c_ * 8,   \
                            &hb[bsel][(w * 16 + i_ * 4) * 128]);                 \
            }                                                                    \
        }

    STAGE2(0, 0)
    bf16x8 aC[2];
    #pragma unroll
    for (int nt = 0; nt < 2; ++nt) aC[nt] = *(const bf16x8*)(a_base + (size_t)nt * 16 * 512);
    asm volatile("s_waitcnt vmcnt(0)" ::: "memory");
    __syncthreads();
    #pragma unroll
    for (int tch = 0; tch < 4; ++tch) {
        const int cur = tch & 1;
        if (tch < 3) STAGE2(cur ^ 1, tch + 1)
        #pragma unroll
        for (int ks = 0; ks < 4; ++ks) {
            const int ksg = tch * 4 + ks;
            bf16x8 aN[2];
            if (ksg < 15) {
                #pragma unroll
                for (int nt = 0; nt < 2; ++nt)
                    aN[nt] = *(const bf16x8*)(a_base + (size_t)nt * 16 * 512 + (ksg + 1) * 32);
            }
            bf16x8 b[4];
            #pragma unroll
            for (int mt = 0; mt < 4; ++mt) {
                const int r = mt * 16 + l15;
                b[mt] = *(const bf16x8*)(&hb[cur][r * 128 + (((ks * 4 + quad) ^ l15) << 3)]);
            }
            #pragma unroll
            for (int nt = 0; nt < 2; ++nt)
                #pragma unroll
                for (int mt = 0; mt < 4; ++mt)
                    acc[nt][mt] = __builtin_amdgcn_mfma_f32_16x16x32_bf16(aC[nt], b[mt], acc[nt][mt], 0, 0, 0);
            if (ksg < 15) {
                #pragma unroll
                for (int nt = 0; nt < 2; ++nt) aC[nt] = aN[nt];
            }
        }
        if (tch < 3) {
            asm volatile("s_waitcnt vmcnt(0)" ::: "memory");
            __syncthreads();             // next chunk landed (all waves)
        }
    }
    #undef STAGE2
    // epilogue: lane holds out-channels chb..chb+3 for site m0+mt*16+l15
    #pragma unroll
    for (int nt = 0; nt < 2; ++nt) {
        const int chb = wn + nt * 16 + quad * 4;
        const float4 bev = *(const float4*)(b_eff + chb);
        const float4 b2v = *(const float4*)(b2 + chb);
        #pragma unroll
        for (int mt = 0; mt < 4; ++mt) {
            const int site = m0 + mt * 16 + l15;
            if (site < nsites) {
                const float4 fv = *(const float4*)(feats + (size_t)site * 128 + chb);
                float4 o;
                o.x = acc[nt][mt][0] + bev.x + b2v.x + fv.x;
                o.y = acc[nt][mt][1] + bev.y + b2v.y + fv.y;
                o.z = acc[nt][mt][2] + bev.z + b2v.z + fv.z;
                o.w = acc[nt][mt][3] + bev.w + b2v.w + fv.w;
                *(float4*)(out + (size_t)site * 128 + chb) = o;
            }
        }
    }
}

// ---------------------------------------------------------------------------
extern "C" void kernel_launch(void* const* d_in, const int* in_sizes, int n_in,
                              void* d_out, int out_size, void* d_ws, size_t ws_size,
                              hipStream_t stream) {
    const float* feats = (const float*)d_in[0];    // [N,128] f32
    const int* nb      = (const int*)d_in[1];      // [N,343] int32
    const float* dw_w  = (const float*)d_in[2];    // [343,128] f32
    const float* dw_b  = (const float*)d_in[3];    // [128]
    const float* ln_g  = (const float*)d_in[4];    // [128]
    const float* ln_b  = (const float*)d_in[5];    // [128]
    const float* w1    = (const float*)d_in[6];    // [128,512]
    const float* b1    = (const float*)d_in[7];    // [512]
    const float* grn_g = (const float*)d_in[8];    // [512]
    const float* grn_b = (const float*)d_in[9];    // [512]
    const float* w2    = (const float*)d_in[10];   // [512,128]
    const float* b2    = (const float*)d_in[11];   // [128]
    float* out = (float*)d_out;
    const int nsites = in_sizes[0] / 128;

    char* ws = (char*)d_ws;
    size_t off = 0;
    u16* xln   = (u16*)(ws + off);  off += (((size_t)(nsites + 128) * 128 * 2) + 255) & ~(size_t)255;
    u16* h     = (u16*)(ws + off);  off += (((size_t)(nsites + 128) * 512 * 2) + 255) & ~(size_t)255;
    u16* featsb= (u16*)(ws + off);  off += (((size_t)nsites * 128 * 2) + 255) & ~(size_t)255;
    u16* dwwb  = (u16*)(ws + off);  off += 343 * 128 * 2 + 128;
    u16* w1t   = (u16*)(ws + off);  off += 512 * 128 * 2;
    u16* w2t   = (u16*)(ws + off);  off += 128 * 512 * 2;
    float* gx_sq = (float*)(ws + off); off += 512 * 4;
    float* scale = (float*)(ws + off); off += 512 * 4;
    float* b_eff = (float*)(ws + off); off += 128 * 4;

    hipMemsetAsync(gx_sq, 0, 512 * sizeof(float), stream);
    hipMemsetAsync(b_eff, 0, 128 * sizeof(float), stream);
    const int nfeat4 = nsites * 32;
    cast_feats_k<<<(nfeat4 + 255) / 256, 256, 0, stream>>>(feats, featsb, nfeat4);
    const int ndww4 = 343 * 32;
    cast_feats_k<<<(ndww4 + 255) / 256, 256, 0, stream>>>(dw_w, dwwb, ndww4);
    transpose_w1_k<<<256, 256, 0, stream>>>(w1, w1t);
    beff_k<<<8, 256, 0, stream>>>(grn_b, w2, b_eff);
    dwln_k<<<(nsites + 7) / 8, 256, 0, stream>>>(featsb, nb, dwwb, dw_b, ln_g, ln_b, xln, nsites);
    const int m1blocks = (nsites + 63) / 64;
    gemm1_k<<<dim3(4, m1blocks), 256, 0, stream>>>(xln, w1t, b1, h, gx_sq, nsites);
    grn_scale_k<<<1, 512, 0, stream>>>(gx_sq, grn_g, scale);
    w2t_k<<<256, 256, 0, stream>>>(scale, w2, w2t);
    const int m2blocks = (nsites + 63) / 64;
    gemm2_k<<<m2blocks, 256, 0, stream>>>(h, w2t, b_eff, b2, feats, out, nsites);
}